// Round 3
// baseline (204.344 us; speedup 1.0000x reference)
//
#include <hip/hip_runtime.h>
#include <hip/hip_bf16.h>

#define NN 8192
#define KIN 512
#define KOUT 256
#define ALPHA 0.2f
#define BK 64
#define NT (NN / BK)

typedef __bf16 bf16x8 __attribute__((ext_vector_type(8)));
typedef float f32x4 __attribute__((ext_vector_type(4)));
typedef unsigned short ushort8_t __attribute__((ext_vector_type(8)));
typedef unsigned short ushort4_t __attribute__((ext_vector_type(4)));

__device__ __forceinline__ float lrelu(float x) { return x > 0.f ? x : ALPHA * x; }

__device__ __forceinline__ unsigned short f2bf(float f) {
  union { float f; unsigned u; } v; v.f = f;
  unsigned r = v.u + 0x7fffu + ((v.u >> 16) & 1u);  // RNE to bf16
  return (unsigned short)(r >> 16);
}
__device__ __forceinline__ float bf2f(unsigned short b) {
  union { unsigned u; float f; } v; v.u = ((unsigned)b) << 16;
  return v.f;
}

// ---------------- k1: Wh = h @ W (fp32), fused src/dst, store Wh as bf16 ----
__global__ __launch_bounds__(512) void k_wh(const float* __restrict__ h,
                                            const float* __restrict__ W,
                                            const float* __restrict__ a1,
                                            const float* __restrict__ a2,
                                            unsigned short* __restrict__ WhB,
                                            float* __restrict__ src,
                                            float* __restrict__ dstv) {
  __shared__ float sA[16][36];    // [k][row]
  __shared__ float sB[16][260];   // [k][col]
  const int tid = threadIdx.x;
  const int wave = tid >> 6;
  const int lane = tid & 63;
  const int bm = blockIdx.x * 32;
  const int arow = tid >> 4;
  const int akk = tid & 15;
  const int bkr = tid >> 5;
  const int bc = (tid & 31) * 8;
  float acc[4][4] = {};
  for (int k0 = 0; k0 < KIN; k0 += 16) {
    float av = h[(size_t)(bm + arow) * KIN + k0 + akk];
    const float4* wp = (const float4*)(W + (size_t)(k0 + bkr) * KOUT + bc);
    float4 w0 = wp[0], w1 = wp[1];
    __syncthreads();
    sA[akk][arow] = av;
    *(float4*)&sB[bkr][bc] = w0;
    *(float4*)&sB[bkr][bc + 4] = w1;
    __syncthreads();
#pragma unroll
    for (int k = 0; k < 16; ++k) {
      float4 a4 = *(const float4*)&sA[k][wave * 4];
      float4 b4 = *(const float4*)&sB[k][lane * 4];
      float aa[4] = {a4.x, a4.y, a4.z, a4.w};
      float bb[4] = {b4.x, b4.y, b4.z, b4.w};
#pragma unroll
      for (int i = 0; i < 4; ++i)
#pragma unroll
        for (int jj = 0; jj < 4; ++jj)
          acc[i][jj] = fmaf(aa[i], bb[jj], acc[i][jj]);
    }
  }
  float4 a1v = *(const float4*)(a1 + lane * 4);
  float4 a2v = *(const float4*)(a2 + lane * 4);
  float sp[4], dp[4];
#pragma unroll
  for (int i = 0; i < 4; ++i) {
    sp[i] = acc[i][0] * a1v.x + acc[i][1] * a1v.y + acc[i][2] * a1v.z + acc[i][3] * a1v.w;
    dp[i] = acc[i][0] * a2v.x + acc[i][1] * a2v.y + acc[i][2] * a2v.z + acc[i][3] * a2v.w;
  }
#pragma unroll
  for (int off = 32; off >= 1; off >>= 1) {
#pragma unroll
    for (int i = 0; i < 4; ++i) {
      sp[i] += __shfl_xor(sp[i], off);
      dp[i] += __shfl_xor(dp[i], off);
    }
  }
  if (lane == 0) {
#pragma unroll
    for (int i = 0; i < 4; ++i) {
      src[bm + wave * 4 + i] = sp[i];
      dstv[bm + wave * 4 + i] = dp[i];
    }
  }
#pragma unroll
  for (int i = 0; i < 4; ++i) {
    ushort4_t pk;
#pragma unroll
    for (int jj = 0; jj < 4; ++jj) pk[jj] = f2bf(acc[i][jj]);
    *(ushort4_t*)(WhB + (size_t)(bm + wave * 4 + i) * KOUT + lane * 4) = pk;
  }
}

// ---------------- k_tr: WhT[c][r] = WhB[r][c] ----------------
__global__ __launch_bounds__(256) void k_tr(const unsigned short* __restrict__ WhB,
                                            unsigned short* __restrict__ WhT) {
  __shared__ unsigned int sX[64][65];
  const int t = threadIdx.x;
  const int r0 = (blockIdx.x & 127) * 64;
  const int c0 = (blockIdx.x >> 7) * 64;
  const int rr = t >> 2;
  const int cq = (t & 3) * 16;
  const ushort8_t* p = (const ushort8_t*)(WhB + (size_t)(r0 + rr) * KOUT + c0 + cq);
  ushort8_t v0 = p[0], v1 = p[1];
#pragma unroll
  for (int i = 0; i < 8; ++i) {
    sX[rr][cq + i] = v0[i];
    sX[rr][cq + 8 + i] = v1[i];
  }
  __syncthreads();
  const int cc = t >> 2;
  const int r8 = (t & 3) * 16;
  ushort8_t o0, o1;
#pragma unroll
  for (int i = 0; i < 8; ++i) {
    o0[i] = (unsigned short)sX[r8 + i][cc];
    o1[i] = (unsigned short)sX[r8 + 8 + i][cc];
  }
  ushort8_t* q = (ushort8_t*)(WhT + (size_t)(c0 + cc) * NN + r0 + r8);
  q[0] = o0;
  q[1] = o1;
}

// ---------------- k_dmax ----------------
__global__ __launch_bounds__(256) void k_dmax(const float* __restrict__ dstv,
                                              float* __restrict__ Dp) {
  __shared__ float red[256];
  const int t = threadIdx.x;
  float m = -3e38f;
  for (int i = t; i < NN; i += 256) m = fmaxf(m, dstv[i]);
  red[t] = m;
  __syncthreads();
  for (int s = 128; s >= 1; s >>= 1) {
    if (t < s) red[t] = fmaxf(red[t], red[t + s]);
    __syncthreads();
  }
  if (t == 0) *Dp = red[0];
}

// ---------------- k_attn: 16 waves/block (wave tile 32x16), LDS-shared A ---
struct Bset { ushort8_t b[2]; };  // [kk]

#define MF(a, b, c) __builtin_amdgcn_mfma_f32_16x16x32_bf16(a, b, c, 0, 0, 0)

// barrier that does NOT drain vmcnt (keeps prefetches in flight)
#define BAR()                                              \
  {                                                        \
    asm volatile("s_waitcnt lgkmcnt(0)" ::: "memory");     \
    __builtin_amdgcn_s_barrier();                          \
    asm volatile("" ::: "memory");                         \
  }

#define LOADB(BS, kt)                                                  \
  {                                                                    \
    const int kb = (kt) * BK + fq * 8;                                 \
    BS.b[0] = *(const ushort8_t*)(bpw + kb);                           \
    BS.b[1] = *(const ushort8_t*)(bpw + kb + 32);                      \
  }

#define LOADADJ(slot, kt)                                              \
  {                                                                    \
    adjR##slot = *(const int2*)(adjp + (size_t)(kt) * BK);             \
    dR##slot = *(const float2*)(dvp + (kt) * BK);                      \
  }

// producer: thread owns (row pr, k-pair pk2) of the 32x64 tile
#define WGEN(aj, dv, buf)                                              \
  {                                                                    \
    float w0 = (aj.x > 0) ? __expf(lrelu(s_r + dv.x) - c_r) : 0.f;     \
    float w1 = (aj.y > 0) ? __expf(lrelu(s_r + dv.y) - c_r) : 0.f;     \
    unsigned short u0 = f2bf(w0), u1 = f2bf(w1);                       \
    lsum += bf2f(u0) + bf2f(u1);                                       \
    unsigned pk = (unsigned)u0 | ((unsigned)u1 << 16);                 \
    *(unsigned*)(sAb + (buf) * 4096 + wbyte) = pk;                     \
  }

#define LDA(cur, mr, kk)                                                        \
  __builtin_bit_cast(bf16x8,                                                    \
    *(const ushort8_t*)(sAb + (cur) * 4096 +                                    \
      ((((mr) * 16 + fr) * 128 + (kk) * 64 + fq * 16) ^ ((fr & 7) << 4))))

#define MSTEP(cur, BS)                                                 \
  {                                                                    \
    bf16x8 a00 = LDA(cur, 0, 0), a01 = LDA(cur, 0, 1);                 \
    bf16x8 a10 = LDA(cur, 1, 0), a11 = LDA(cur, 1, 1);                 \
    acc0 = MF(a00, BS.b[0], acc0);                                     \
    acc0 = MF(a01, BS.b[1], acc0);                                     \
    acc1 = MF(a10, BS.b[0], acc1);                                     \
    acc1 = MF(a11, BS.b[1], acc1);                                     \
  }

__global__ __launch_bounds__(1024) void k_attn(const int* __restrict__ adj,
                                               const unsigned short* __restrict__ WhT,
                                               const float* __restrict__ src,
                                               const float* __restrict__ dstv,
                                               const float* __restrict__ Dp,
                                               float* __restrict__ out) {
  __shared__ unsigned short sA[2][32][BK];  // 8 KB, XOR-swizzled rows
  __shared__ float sL[32];
  char* sAb = (char*)&sA[0][0][0];
  const int tid = threadIdx.x;
  const int lane = tid & 63;
  const int wave = tid >> 6;      // 0..15
  const int r0 = blockIdx.x * 32;
  const float D = *Dp;

  // producer role: row pr (0..31), k-pair pk2
  const int pr = tid >> 5;
  const int pk2 = (tid & 31) * 2;
  const float s_r = src[r0 + pr];
  const float c_r = lrelu(s_r + D);
  const int* adjp = adj + (size_t)(r0 + pr) * NN + pk2;
  const float* dvp = dstv + pk2;
  const int wbyte = ((pr * (BK * 2) + pk2 * 2) ^ ((pr & 7) << 4));

  // consumer: wave owns cols c0..c0+15
  const int fr = lane & 15;
  const int fq = lane >> 4;
  const unsigned short* bpw = WhT + (size_t)(wave * 16 + fr) * NN;

  f32x4 acc0 = {0.f, 0.f, 0.f, 0.f};
  f32x4 acc1 = acc0;
  float lsum = 0.f;

  int2 adjR0, adjR1;
  float2 dR0, dR1;
  Bset B0, B1;

  // prologue: tile 0 inline -> buf0; prefetch adj tiles 1,2; B(0)
  {
    int2 aT = *(const int2*)adjp;
    float2 dT = *(const float2*)dvp;
    WGEN(aT, dT, 0);
  }
  LOADADJ(1, 1);
  LOADADJ(0, 2);
  LOADB(B0, 0);
  BAR();

#pragma unroll 1
  for (int t = 0; t < NT; t += 2) {
    // phase A: MFMA tile t (buf0), gen tile t+1 -> buf1
    {
      const int tb = (t + 1 < NT) ? t + 1 : NT - 1;
      LOADB(B1, tb);
      MSTEP(0, B0);
      WGEN(adjR1, dR1, 1);  // t+1 <= NT-1 always
      const int tp = (t + 3 < NT) ? t + 3 : NT - 1;
      LOADADJ(1, tp);
      BAR();
    }
    // phase B: MFMA tile t+1 (buf1), gen tile t+2 -> buf0
    {
      const int tb = (t + 2 < NT) ? t + 2 : NT - 1;
      LOADB(B0, tb);
      MSTEP(1, B1);
      if (t + 2 < NT) { WGEN(adjR0, dR0, 0); }
      const int tp = (t + 4 < NT) ? t + 4 : NT - 1;
      LOADADJ(0, tp);
      BAR();
    }
  }

  // row-sum reduce across the 32 threads sharing a row (half-wave)
#pragma unroll
  for (int off = 1; off <= 16; off <<= 1) lsum += __shfl_xor(lsum, off, 32);
  if ((tid & 31) == 0) sL[pr] = lsum;
  __syncthreads();

  // epilogue: normalize, ELU, store
  const f32x4 accs[2] = {acc0, acc1};
#pragma unroll
  for (int mr = 0; mr < 2; ++mr) {
#pragma unroll
    for (int r = 0; r < 4; ++r) {
      const int row = mr * 16 + fq * 4 + r;
      const float l = sL[row];
      const int col = wave * 16 + fr;
      float v = accs[mr][r] / l;
      v = v > 0.f ? v : __expf(v) - 1.f;
      out[(size_t)(r0 + row) * KOUT + col] = v;
    }
  }
}

extern "C" void kernel_launch(void* const* d_in, const int* in_sizes, int n_in,
                              void* d_out, int out_size, void* d_ws, size_t ws_size,
                              hipStream_t stream) {
  const float* h = (const float*)d_in[0];
  const int* adj = (const int*)d_in[1];
  const float* W = (const float*)d_in[2];
  const float* a1 = (const float*)d_in[3];
  const float* a2 = (const float*)d_in[4];
  float* out = (float*)d_out;

  unsigned short* WhB = (unsigned short*)d_ws;
  unsigned short* WhT = WhB + (size_t)NN * KOUT;
  float* src = (float*)(WhT + (size_t)NN * KOUT);
  float* dstv = src + NN;
  float* Dp = dstv + NN;

  hipLaunchKernelGGL(k_wh, dim3(NN / 32), dim3(512), 0, stream, h, W, a1, a2, WhB, src, dstv);
  hipLaunchKernelGGL(k_tr, dim3(512), dim3(256), 0, stream, WhB, WhT);
  hipLaunchKernelGGL(k_dmax, dim3(1), dim3(256), 0, stream, dstv, Dp);
  hipLaunchKernelGGL(k_attn, dim3(NN / 32), dim3(1024), 0, stream, adj, WhT, src, dstv, Dp, out);
}

// Round 4
// 203.372 us; speedup vs baseline: 1.0048x; 1.0048x over previous
//
#include <hip/hip_runtime.h>
#include <hip/hip_bf16.h>

#define NN 8192
#define KIN 512
#define KOUT 256
#define ALPHA 0.2f
#define BK 64
#define NT (NN / BK)

typedef __bf16 bf16x8 __attribute__((ext_vector_type(8)));
typedef float f32x4 __attribute__((ext_vector_type(4)));
typedef unsigned short ushort8_t __attribute__((ext_vector_type(8)));
typedef unsigned short ushort4_t __attribute__((ext_vector_type(4)));
typedef int int2v __attribute__((ext_vector_type(2)));

__device__ __forceinline__ float lrelu(float x) { return x > 0.f ? x : ALPHA * x; }

__device__ __forceinline__ unsigned short f2bf(float f) {
  union { float f; unsigned u; } v; v.f = f;
  unsigned r = v.u + 0x7fffu + ((v.u >> 16) & 1u);  // RNE to bf16
  return (unsigned short)(r >> 16);
}
__device__ __forceinline__ float bf2f(unsigned short b) {
  union { unsigned u; float f; } v; v.u = ((unsigned)b) << 16;
  return v.f;
}

// ---------------- k1: Wh = h @ W (fp32), fused src/dst, store Wh as bf16 ----
__global__ __launch_bounds__(512) void k_wh(const float* __restrict__ h,
                                            const float* __restrict__ W,
                                            const float* __restrict__ a1,
                                            const float* __restrict__ a2,
                                            unsigned short* __restrict__ WhB,
                                            float* __restrict__ src,
                                            float* __restrict__ dstv) {
  __shared__ float sA[16][36];    // [k][row]
  __shared__ float sB[16][260];   // [k][col]
  const int tid = threadIdx.x;
  const int wave = tid >> 6;
  const int lane = tid & 63;
  const int bm = blockIdx.x * 32;
  const int arow = tid >> 4;
  const int akk = tid & 15;
  const int bkr = tid >> 5;
  const int bc = (tid & 31) * 8;
  float acc[4][4] = {};
  for (int k0 = 0; k0 < KIN; k0 += 16) {
    float av = h[(size_t)(bm + arow) * KIN + k0 + akk];
    const float4* wp = (const float4*)(W + (size_t)(k0 + bkr) * KOUT + bc);
    float4 w0 = wp[0], w1 = wp[1];
    __syncthreads();
    sA[akk][arow] = av;
    *(float4*)&sB[bkr][bc] = w0;
    *(float4*)&sB[bkr][bc + 4] = w1;
    __syncthreads();
#pragma unroll
    for (int k = 0; k < 16; ++k) {
      float4 a4 = *(const float4*)&sA[k][wave * 4];
      float4 b4 = *(const float4*)&sB[k][lane * 4];
      float aa[4] = {a4.x, a4.y, a4.z, a4.w};
      float bb[4] = {b4.x, b4.y, b4.z, b4.w};
#pragma unroll
      for (int i = 0; i < 4; ++i)
#pragma unroll
        for (int jj = 0; jj < 4; ++jj)
          acc[i][jj] = fmaf(aa[i], bb[jj], acc[i][jj]);
    }
  }
  float4 a1v = *(const float4*)(a1 + lane * 4);
  float4 a2v = *(const float4*)(a2 + lane * 4);
  float sp[4], dp[4];
#pragma unroll
  for (int i = 0; i < 4; ++i) {
    sp[i] = acc[i][0] * a1v.x + acc[i][1] * a1v.y + acc[i][2] * a1v.z + acc[i][3] * a1v.w;
    dp[i] = acc[i][0] * a2v.x + acc[i][1] * a2v.y + acc[i][2] * a2v.z + acc[i][3] * a2v.w;
  }
#pragma unroll
  for (int off = 32; off >= 1; off >>= 1) {
#pragma unroll
    for (int i = 0; i < 4; ++i) {
      sp[i] += __shfl_xor(sp[i], off);
      dp[i] += __shfl_xor(dp[i], off);
    }
  }
  if (lane == 0) {
#pragma unroll
    for (int i = 0; i < 4; ++i) {
      src[bm + wave * 4 + i] = sp[i];
      dstv[bm + wave * 4 + i] = dp[i];
    }
  }
#pragma unroll
  for (int i = 0; i < 4; ++i) {
    ushort4_t pk;
#pragma unroll
    for (int jj = 0; jj < 4; ++jj) pk[jj] = f2bf(acc[i][jj]);
    *(ushort4_t*)(WhB + (size_t)(bm + wave * 4 + i) * KOUT + lane * 4) = pk;
  }
}

// ---------------- k_tr: WhT[c][r] = WhB[r][c] ----------------
__global__ __launch_bounds__(256) void k_tr(const unsigned short* __restrict__ WhB,
                                            unsigned short* __restrict__ WhT) {
  __shared__ unsigned int sX[64][65];
  const int t = threadIdx.x;
  const int r0 = (blockIdx.x & 127) * 64;
  const int c0 = (blockIdx.x >> 7) * 64;
  const int rr = t >> 2;
  const int cq = (t & 3) * 16;
  const ushort8_t* p = (const ushort8_t*)(WhB + (size_t)(r0 + rr) * KOUT + c0 + cq);
  ushort8_t v0 = p[0], v1 = p[1];
#pragma unroll
  for (int i = 0; i < 8; ++i) {
    sX[rr][cq + i] = v0[i];
    sX[rr][cq + 8 + i] = v1[i];
  }
  __syncthreads();
  const int cc = t >> 2;
  const int r8 = (t & 3) * 16;
  ushort8_t o0, o1;
#pragma unroll
  for (int i = 0; i < 8; ++i) {
    o0[i] = (unsigned short)sX[r8 + i][cc];
    o1[i] = (unsigned short)sX[r8 + 8 + i][cc];
  }
  ushort8_t* q = (ushort8_t*)(WhT + (size_t)(c0 + cc) * NN + r0 + r8);
  q[0] = o0;
  q[1] = o1;
}

// ---------------- k_dmax ----------------
__global__ __launch_bounds__(256) void k_dmax(const float* __restrict__ dstv,
                                              float* __restrict__ Dp) {
  __shared__ float red[256];
  const int t = threadIdx.x;
  float m = -3e38f;
  for (int i = t; i < NN; i += 256) m = fmaxf(m, dstv[i]);
  red[t] = m;
  __syncthreads();
  for (int s = 128; s >= 1; s >>= 1) {
    if (t < s) red[t] = fmaxf(red[t], red[t + s]);
    __syncthreads();
  }
  if (t == 0) *Dp = red[0];
}

// ---------------- k_attn: 16 waves, nt-adj, 2-phase slack both streams ----
struct Bset { ushort8_t b[2]; };  // [kk]

#define MF(a, b, c) __builtin_amdgcn_mfma_f32_16x16x32_bf16(a, b, c, 0, 0, 0)

// barrier that does NOT drain vmcnt (keeps prefetches in flight)
#define BAR()                                              \
  {                                                        \
    asm volatile("s_waitcnt lgkmcnt(0)" ::: "memory");     \
    __builtin_amdgcn_s_barrier();                          \
    asm volatile("" ::: "memory");                         \
  }

#define LOADB(BS, kt)                                                  \
  {                                                                    \
    const int kb = (kt) * BK + fq * 8;                                 \
    BS.b[0] = *(const ushort8_t*)(bpw + kb);                           \
    BS.b[1] = *(const ushort8_t*)(bpw + kb + 32);                      \
  }

// non-temporal adj (zero-reuse stream: keep out of L2 so WhT stays resident)
#define LOADADJ(slot, kt)                                              \
  {                                                                    \
    adjR##slot =                                                       \
        __builtin_nontemporal_load((const int2v*)(adjp + (size_t)(kt) * BK)); \
    dR##slot = *(const float2*)(dvp + (kt) * BK);                      \
  }

// producer: thread owns (row pr, k-pair pk2) of the 32x64 tile
#define WGEN(aj, dv, buf)                                              \
  {                                                                    \
    float w0 = (aj.x > 0) ? __expf(lrelu(s_r + dv.x) - c_r) : 0.f;     \
    float w1 = (aj.y > 0) ? __expf(lrelu(s_r + dv.y) - c_r) : 0.f;     \
    unsigned short u0 = f2bf(w0), u1 = f2bf(w1);                       \
    lsum += bf2f(u0) + bf2f(u1);                                       \
    unsigned pk = (unsigned)u0 | ((unsigned)u1 << 16);                 \
    *(unsigned*)(sAb + (buf) * 4096 + wbyte) = pk;                     \
  }

#define LDA(cur, mr, kk)                                                        \
  __builtin_bit_cast(bf16x8,                                                    \
    *(const ushort8_t*)(sAb + (cur) * 4096 +                                    \
      ((((mr) * 16 + fr) * 128 + (kk) * 64 + fq * 16) ^ ((fr & 7) << 4))))

#define MSTEP(cur, BS)                                                 \
  {                                                                    \
    bf16x8 a00 = LDA(cur, 0, 0), a01 = LDA(cur, 0, 1);                 \
    bf16x8 a10 = LDA(cur, 1, 0), a11 = LDA(cur, 1, 1);                 \
    acc0 = MF(a00, BS.b[0], acc0);                                     \
    acc0 = MF(a01, BS.b[1], acc0);                                     \
    acc1 = MF(a10, BS.b[0], acc1);                                     \
    acc1 = MF(a11, BS.b[1], acc1);                                     \
  }

__global__ __launch_bounds__(1024) void k_attn(const int* __restrict__ adj,
                                               const unsigned short* __restrict__ WhT,
                                               const float* __restrict__ src,
                                               const float* __restrict__ dstv,
                                               const float* __restrict__ Dp,
                                               float* __restrict__ out) {
  __shared__ unsigned short sA[2][32][BK];  // 8 KB, XOR-swizzled rows
  __shared__ float sL[32];
  char* sAb = (char*)&sA[0][0][0];
  const int tid = threadIdx.x;
  const int lane = tid & 63;
  const int wave = tid >> 6;      // 0..15
  const int r0 = blockIdx.x * 32;
  const float D = *Dp;

  // producer role: row pr (0..31), k-pair pk2
  const int pr = tid >> 5;
  const int pk2 = (tid & 31) * 2;
  const float s_r = src[r0 + pr];
  const float c_r = lrelu(s_r + D);
  const int* adjp = adj + (size_t)(r0 + pr) * NN + pk2;
  const float* dvp = dstv + pk2;
  const int wbyte = ((pr * (BK * 2) + pk2 * 2) ^ ((pr & 7) << 4));

  // consumer: wave owns cols wave*16..wave*16+15
  const int fr = lane & 15;
  const int fq = lane >> 4;
  const unsigned short* bpw = WhT + (size_t)(wave * 16 + fr) * NN;

  f32x4 acc0 = {0.f, 0.f, 0.f, 0.f};
  f32x4 acc1 = acc0;
  float lsum = 0.f;

  int2v adjR0, adjR1;
  float2 dR0, dR1;
  Bset B0, B1;

  // prologue: gen tile 0 -> buf0; B slots for tiles 0,1; adj slots for 1,2
  {
    int2v aT = *(const int2v*)adjp;
    float2 dT = *(const float2*)dvp;
    WGEN(aT, dT, 0);
  }
  LOADB(B0, 0);
  LOADB(B1, 1);
  LOADADJ(0, 1);
  LOADADJ(1, 2);
  BAR();

  // phase p: MSTEP tile p (buf p%2, B slot p%2); WGEN tile p+1 (adj slot p%2)
  // -> buf (p+1)%2; issue B(p+2) into slot p%2, adj(p+3) into slot p%2.
#pragma unroll 1
  for (int p = 0; p < NT; p += 2) {
    // even phase (slots 0)
    {
      MSTEP(0, B0);
      WGEN(adjR0, dR0, 1);  // tile p+1 <= NT-1 always (p <= NT-2)
      const int tb = (p + 2 < NT) ? p + 2 : NT - 1;
      LOADB(B0, tb);
      const int ta = (p + 3 < NT) ? p + 3 : NT - 1;
      LOADADJ(0, ta);
      BAR();
    }
    // odd phase (slots 1)
    {
      MSTEP(1, B1);
      if (p + 2 < NT) { WGEN(adjR1, dR1, 0); }  // tile p+2
      const int tb = (p + 3 < NT) ? p + 3 : NT - 1;
      LOADB(B1, tb);
      const int ta = (p + 4 < NT) ? p + 4 : NT - 1;
      LOADADJ(1, ta);
      BAR();
    }
  }

  // row-sum reduce across the 32 threads sharing a row (half-wave)
#pragma unroll
  for (int off = 1; off <= 16; off <<= 1) lsum += __shfl_xor(lsum, off, 32);
  if ((tid & 31) == 0) sL[pr] = lsum;
  __syncthreads();

  // epilogue: normalize, ELU, store
  const f32x4 accs[2] = {acc0, acc1};
#pragma unroll
  for (int mr = 0; mr < 2; ++mr) {
#pragma unroll
    for (int r = 0; r < 4; ++r) {
      const int row = mr * 16 + fq * 4 + r;
      const float l = sL[row];
      const int col = wave * 16 + fr;
      float v = accs[mr][r] / l;
      v = v > 0.f ? v : __expf(v) - 1.f;
      out[(size_t)(r0 + row) * KOUT + col] = v;
    }
  }
}

extern "C" void kernel_launch(void* const* d_in, const int* in_sizes, int n_in,
                              void* d_out, int out_size, void* d_ws, size_t ws_size,
                              hipStream_t stream) {
  const float* h = (const float*)d_in[0];
  const int* adj = (const int*)d_in[1];
  const float* W = (const float*)d_in[2];
  const float* a1 = (const float*)d_in[3];
  const float* a2 = (const float*)d_in[4];
  float* out = (float*)d_out;

  unsigned short* WhB = (unsigned short*)d_ws;
  unsigned short* WhT = WhB + (size_t)NN * KOUT;
  float* src = (float*)(WhT + (size_t)NN * KOUT);
  float* dstv = src + NN;
  float* Dp = dstv + NN;

  hipLaunchKernelGGL(k_wh, dim3(NN / 32), dim3(512), 0, stream, h, W, a1, a2, WhB, src, dstv);
  hipLaunchKernelGGL(k_tr, dim3(512), dim3(256), 0, stream, WhB, WhT);
  hipLaunchKernelGGL(k_dmax, dim3(1), dim3(256), 0, stream, dstv, Dp);
  hipLaunchKernelGGL(k_attn, dim3(NN / 32), dim3(1024), 0, stream, adj, WhT, src, dstv, Dp, out);
}

// Round 5
// 188.683 us; speedup vs baseline: 1.0830x; 1.0779x over previous
//
#include <hip/hip_runtime.h>
#include <hip/hip_bf16.h>

#define NN 8192
#define KIN 512
#define KOUT 256
#define ALPHA 0.2f
#define BK 64
#define NT (NN / BK)

typedef __bf16 bf16x8 __attribute__((ext_vector_type(8)));
typedef float f32x4 __attribute__((ext_vector_type(4)));
typedef unsigned short ushort8_t __attribute__((ext_vector_type(8)));
typedef unsigned short ushort4_t __attribute__((ext_vector_type(4)));
typedef int int2v __attribute__((ext_vector_type(2)));

__device__ __forceinline__ float lrelu(float x) { return x > 0.f ? x : ALPHA * x; }

__device__ __forceinline__ unsigned short f2bf(float f) {
  union { float f; unsigned u; } v; v.f = f;
  unsigned r = v.u + 0x7fffu + ((v.u >> 16) & 1u);  // RNE to bf16
  return (unsigned short)(r >> 16);
}
__device__ __forceinline__ float bf2f(unsigned short b) {
  union { unsigned u; float f; } v; v.u = ((unsigned)b) << 16;
  return v.f;
}

// ---------------- k1: Wh = h @ W (fp32), fused src/dst, store Wh as bf16 ----
__global__ __launch_bounds__(512) void k_wh(const float* __restrict__ h,
                                            const float* __restrict__ W,
                                            const float* __restrict__ a1,
                                            const float* __restrict__ a2,
                                            unsigned short* __restrict__ WhB,
                                            float* __restrict__ src,
                                            float* __restrict__ dstv) {
  __shared__ float sA[16][36];    // [k][row]
  __shared__ float sB[16][260];   // [k][col]
  const int tid = threadIdx.x;
  const int wave = tid >> 6;
  const int lane = tid & 63;
  const int bm = blockIdx.x * 32;
  const int arow = tid >> 4;
  const int akk = tid & 15;
  const int bkr = tid >> 5;
  const int bc = (tid & 31) * 8;
  float acc[4][4] = {};
  for (int k0 = 0; k0 < KIN; k0 += 16) {
    float av = h[(size_t)(bm + arow) * KIN + k0 + akk];
    const float4* wp = (const float4*)(W + (size_t)(k0 + bkr) * KOUT + bc);
    float4 w0 = wp[0], w1 = wp[1];
    __syncthreads();
    sA[akk][arow] = av;
    *(float4*)&sB[bkr][bc] = w0;
    *(float4*)&sB[bkr][bc + 4] = w1;
    __syncthreads();
#pragma unroll
    for (int k = 0; k < 16; ++k) {
      float4 a4 = *(const float4*)&sA[k][wave * 4];
      float4 b4 = *(const float4*)&sB[k][lane * 4];
      float aa[4] = {a4.x, a4.y, a4.z, a4.w};
      float bb[4] = {b4.x, b4.y, b4.z, b4.w};
#pragma unroll
      for (int i = 0; i < 4; ++i)
#pragma unroll
        for (int jj = 0; jj < 4; ++jj)
          acc[i][jj] = fmaf(aa[i], bb[jj], acc[i][jj]);
    }
  }
  float4 a1v = *(const float4*)(a1 + lane * 4);
  float4 a2v = *(const float4*)(a2 + lane * 4);
  float sp[4], dp[4];
#pragma unroll
  for (int i = 0; i < 4; ++i) {
    sp[i] = acc[i][0] * a1v.x + acc[i][1] * a1v.y + acc[i][2] * a1v.z + acc[i][3] * a1v.w;
    dp[i] = acc[i][0] * a2v.x + acc[i][1] * a2v.y + acc[i][2] * a2v.z + acc[i][3] * a2v.w;
  }
#pragma unroll
  for (int off = 32; off >= 1; off >>= 1) {
#pragma unroll
    for (int i = 0; i < 4; ++i) {
      sp[i] += __shfl_xor(sp[i], off);
      dp[i] += __shfl_xor(dp[i], off);
    }
  }
  if (lane == 0) {
#pragma unroll
    for (int i = 0; i < 4; ++i) {
      src[bm + wave * 4 + i] = sp[i];
      dstv[bm + wave * 4 + i] = dp[i];
    }
  }
#pragma unroll
  for (int i = 0; i < 4; ++i) {
    ushort4_t pk;
#pragma unroll
    for (int jj = 0; jj < 4; ++jj) pk[jj] = f2bf(acc[i][jj]);
    *(ushort4_t*)(WhB + (size_t)(bm + wave * 4 + i) * KOUT + lane * 4) = pk;
  }
}

// ---------------- k_tr: WhT[c][r] = WhB[r][c] ----------------
__global__ __launch_bounds__(256) void k_tr(const unsigned short* __restrict__ WhB,
                                            unsigned short* __restrict__ WhT) {
  __shared__ unsigned int sX[64][65];
  const int t = threadIdx.x;
  const int r0 = (blockIdx.x & 127) * 64;
  const int c0 = (blockIdx.x >> 7) * 64;
  const int rr = t >> 2;
  const int cq = (t & 3) * 16;
  const ushort8_t* p = (const ushort8_t*)(WhB + (size_t)(r0 + rr) * KOUT + c0 + cq);
  ushort8_t v0 = p[0], v1 = p[1];
#pragma unroll
  for (int i = 0; i < 8; ++i) {
    sX[rr][cq + i] = v0[i];
    sX[rr][cq + 8 + i] = v1[i];
  }
  __syncthreads();
  const int cc = t >> 2;
  const int r8 = (t & 3) * 16;
  ushort8_t o0, o1;
#pragma unroll
  for (int i = 0; i < 8; ++i) {
    o0[i] = (unsigned short)sX[r8 + i][cc];
    o1[i] = (unsigned short)sX[r8 + 8 + i][cc];
  }
  ushort8_t* q = (ushort8_t*)(WhT + (size_t)(c0 + cc) * NN + r0 + r8);
  q[0] = o0;
  q[1] = o1;
}

// ---------------- k_dmax ----------------
__global__ __launch_bounds__(256) void k_dmax(const float* __restrict__ dstv,
                                              float* __restrict__ Dp) {
  __shared__ float red[256];
  const int t = threadIdx.x;
  float m = -3e38f;
  for (int i = t; i < NN; i += 256) m = fmaxf(m, dstv[i]);
  red[t] = m;
  __syncthreads();
  for (int s = 128; s >= 1; s >>= 1) {
    if (t < s) red[t] = fmaxf(red[t], red[t + s]);
    __syncthreads();
  }
  if (t == 0) *Dp = red[0];
}

// ---- k_attn: 16 waves, per-block phase rotation, dstv in LDS -------------
struct Bset { ushort8_t b[2]; };  // [kk]

#define MF(a, b, c) __builtin_amdgcn_mfma_f32_16x16x32_bf16(a, b, c, 0, 0, 0)

// barrier that does NOT drain vmcnt (keeps prefetches in flight)
#define BAR()                                              \
  {                                                        \
    asm volatile("s_waitcnt lgkmcnt(0)" ::: "memory");     \
    __builtin_amdgcn_s_barrier();                          \
    asm volatile("" ::: "memory");                         \
  }

// virtual phase t -> physical k-tile (per-block rotation decontends L2)
#define TI(t) (((t) + ph0) & (NT - 1))

#define LOADB(BS, kt)                                                  \
  {                                                                    \
    const int kb = (kt) * BK + fq * 8;                                 \
    BS.b[0] = *(const ushort8_t*)(bpw + kb);                           \
    BS.b[1] = *(const ushort8_t*)(bpw + kb + 32);                      \
  }

// non-temporal adj (zero-reuse stream)
#define LOADADJ(slot, kt)                                              \
  {                                                                    \
    adjR##slot =                                                       \
        __builtin_nontemporal_load((const int2v*)(adjp + (size_t)(kt) * BK)); \
  }

// producer: thread owns (row pr, k-pair pk2); dstv from LDS
#define WGEN(aj, kt, buf)                                              \
  {                                                                    \
    float2 dv = *(const float2*)&sD[(kt) * BK + pk2];                  \
    float w0 = (aj.x > 0) ? __expf(lrelu(s_r + dv.x) - c_r) : 0.f;     \
    float w1 = (aj.y > 0) ? __expf(lrelu(s_r + dv.y) - c_r) : 0.f;     \
    unsigned short u0 = f2bf(w0), u1 = f2bf(w1);                       \
    lsum += bf2f(u0) + bf2f(u1);                                       \
    unsigned pk = (unsigned)u0 | ((unsigned)u1 << 16);                 \
    *(unsigned*)(sAb + (buf) * 4096 + wbyte) = pk;                     \
  }

#define LDA(cur, mr, kk)                                                        \
  __builtin_bit_cast(bf16x8,                                                    \
    *(const ushort8_t*)(sAb + (cur) * 4096 +                                    \
      ((((mr) * 16 + fr) * 128 + (kk) * 64 + fq * 16) ^ ((fr & 7) << 4))))

#define MSTEP(cur, BS)                                                 \
  {                                                                    \
    bf16x8 a00 = LDA(cur, 0, 0), a01 = LDA(cur, 0, 1);                 \
    bf16x8 a10 = LDA(cur, 1, 0), a11 = LDA(cur, 1, 1);                 \
    acc0 = MF(a00, BS.b[0], acc0);                                     \
    acc0 = MF(a01, BS.b[1], acc0);                                     \
    acc1 = MF(a10, BS.b[0], acc1);                                     \
    acc1 = MF(a11, BS.b[1], acc1);                                     \
  }

__global__ __launch_bounds__(1024) void k_attn(const int* __restrict__ adj,
                                               const unsigned short* __restrict__ WhT,
                                               const float* __restrict__ src,
                                               const float* __restrict__ dstv,
                                               const float* __restrict__ Dp,
                                               float* __restrict__ out) {
  __shared__ unsigned short sA[2][32][BK];  // 8 KB, XOR-swizzled rows
  __shared__ float sD[NN];                  // 32 KB: dstv staged once
  __shared__ float sL[32];
  char* sAb = (char*)&sA[0][0][0];
  const int tid = threadIdx.x;
  const int lane = tid & 63;
  const int wave = tid >> 6;      // 0..15
  const int r0 = blockIdx.x * 32;
  const int ph0 = blockIdx.x & (NT - 1);
  const float D = *Dp;

  // stage dstv -> LDS (coalesced, once)
  {
    float4 v0 = *(const float4*)(dstv + tid * 8);
    float4 v1 = *(const float4*)(dstv + tid * 8 + 4);
    *(float4*)&sD[tid * 8] = v0;
    *(float4*)&sD[tid * 8 + 4] = v1;
  }

  // producer role: row pr (0..31), k-pair pk2
  const int pr = tid >> 5;
  const int pk2 = (tid & 31) * 2;
  const float s_r = src[r0 + pr];
  const float c_r = lrelu(s_r + D);
  const int* adjp = adj + (size_t)(r0 + pr) * NN + pk2;
  const int wbyte = ((pr * (BK * 2) + pk2 * 2) ^ ((pr & 7) << 4));

  // consumer: wave owns cols wave*16..wave*16+15
  const int fr = lane & 15;
  const int fq = lane >> 4;
  const unsigned short* bpw = WhT + (size_t)(wave * 16 + fr) * NN;

  f32x4 acc0 = {0.f, 0.f, 0.f, 0.f};
  f32x4 acc1 = acc0;
  float lsum = 0.f;

  int2v adjR0, adjR1;
  Bset B0, B1;

  // prologue: gen tile TI(0) -> buf0 (global dstv read; sD not synced yet);
  // B slots for tiles 0,1; adj slots for 1,2
  {
    int2v aT = *(const int2v*)(adjp + (size_t)TI(0) * BK);
    float2 dT = *(const float2*)(dstv + TI(0) * BK + pk2);
    float w0 = (aT.x > 0) ? __expf(lrelu(s_r + dT.x) - c_r) : 0.f;
    float w1 = (aT.y > 0) ? __expf(lrelu(s_r + dT.y) - c_r) : 0.f;
    unsigned short u0 = f2bf(w0), u1 = f2bf(w1);
    lsum += bf2f(u0) + bf2f(u1);
    unsigned pk = (unsigned)u0 | ((unsigned)u1 << 16);
    *(unsigned*)(sAb + wbyte) = pk;
  }
  LOADB(B0, TI(0));
  LOADB(B1, TI(1));
  LOADADJ(0, TI(1));
  LOADADJ(1, TI(2));
  BAR();

  // phase p: MSTEP tile p (buf p%2, B slot p%2); WGEN tile p+1 (adj slot p%2)
  // -> buf (p+1)%2; issue B(p+2) into slot p%2, adj(p+3) into slot p%2.
#pragma unroll 1
  for (int p = 0; p < NT; p += 2) {
    // even phase (slots 0)
    {
      MSTEP(0, B0);
      WGEN(adjR0, TI(p + 1), 1);  // tile p+1 <= NT-1 always
      const int tb = (p + 2 < NT) ? p + 2 : NT - 1;
      LOADB(B0, TI(tb));
      const int ta = (p + 3 < NT) ? p + 3 : NT - 1;
      LOADADJ(0, TI(ta));
      BAR();
    }
    // odd phase (slots 1)
    {
      MSTEP(1, B1);
      if (p + 2 < NT) { WGEN(adjR1, TI(p + 2), 0); }
      const int tb = (p + 3 < NT) ? p + 3 : NT - 1;
      LOADB(B1, TI(tb));
      const int ta = (p + 4 < NT) ? p + 4 : NT - 1;
      LOADADJ(1, TI(ta));
      BAR();
    }
  }

  // row-sum reduce across the 32 threads sharing a row (half-wave)
#pragma unroll
  for (int off = 1; off <= 16; off <<= 1) lsum += __shfl_xor(lsum, off, 32);
  if ((tid & 31) == 0) sL[pr] = lsum;
  __syncthreads();

  // epilogue: normalize, ELU, store
  const f32x4 accs[2] = {acc0, acc1};
#pragma unroll
  for (int mr = 0; mr < 2; ++mr) {
#pragma unroll
    for (int r = 0; r < 4; ++r) {
      const int row = mr * 16 + fq * 4 + r;
      const float l = sL[row];
      const int col = wave * 16 + fr;
      float v = accs[mr][r] / l;
      v = v > 0.f ? v : __expf(v) - 1.f;
      out[(size_t)(r0 + row) * KOUT + col] = v;
    }
  }
}

extern "C" void kernel_launch(void* const* d_in, const int* in_sizes, int n_in,
                              void* d_out, int out_size, void* d_ws, size_t ws_size,
                              hipStream_t stream) {
  const float* h = (const float*)d_in[0];
  const int* adj = (const int*)d_in[1];
  const float* W = (const float*)d_in[2];
  const float* a1 = (const float*)d_in[3];
  const float* a2 = (const float*)d_in[4];
  float* out = (float*)d_out;

  unsigned short* WhB = (unsigned short*)d_ws;
  unsigned short* WhT = WhB + (size_t)NN * KOUT;
  float* src = (float*)(WhT + (size_t)NN * KOUT);
  float* dstv = src + NN;
  float* Dp = dstv + NN;

  hipLaunchKernelGGL(k_wh, dim3(NN / 32), dim3(512), 0, stream, h, W, a1, a2, WhB, src, dstv);
  hipLaunchKernelGGL(k_tr, dim3(512), dim3(256), 0, stream, WhB, WhT);
  hipLaunchKernelGGL(k_dmax, dim3(1), dim3(256), 0, stream, dstv, Dp);
  hipLaunchKernelGGL(k_attn, dim3(NN / 32), dim3(1024), 0, stream, adj, WhT, src, dstv, Dp, out);
}

// Round 6
// 186.168 us; speedup vs baseline: 1.0976x; 1.0135x over previous
//
#include <hip/hip_runtime.h>
#include <hip/hip_bf16.h>

#define NN 8192
#define KIN 512
#define KOUT 256
#define ALPHA 0.2f
#define BK 64
#define NT (NN / BK)

typedef __bf16 bf16x8 __attribute__((ext_vector_type(8)));
typedef float f32x4 __attribute__((ext_vector_type(4)));
typedef unsigned short ushort8_t __attribute__((ext_vector_type(8)));
typedef unsigned short ushort4_t __attribute__((ext_vector_type(4)));
typedef int int4v __attribute__((ext_vector_type(4)));

__device__ __forceinline__ float lrelu(float x) { return x > 0.f ? x : ALPHA * x; }

__device__ __forceinline__ unsigned short f2bf(float f) {
  union { float f; unsigned u; } v; v.f = f;
  unsigned r = v.u + 0x7fffu + ((v.u >> 16) & 1u);  // RNE to bf16
  return (unsigned short)(r >> 16);
}
__device__ __forceinline__ float bf2f(unsigned short b) {
  union { unsigned u; float f; } v; v.u = ((unsigned)b) << 16;
  return v.f;
}

// ---------------- k1: Wh = h @ W (fp32), fused src/dst, store Wh as bf16 ----
__global__ __launch_bounds__(512) void k_wh(const float* __restrict__ h,
                                            const float* __restrict__ W,
                                            const float* __restrict__ a1,
                                            const float* __restrict__ a2,
                                            unsigned short* __restrict__ WhB,
                                            float* __restrict__ src,
                                            float* __restrict__ dstv) {
  __shared__ float sA[16][36];    // [k][row]
  __shared__ float sB[16][260];   // [k][col]
  const int tid = threadIdx.x;
  const int wave = tid >> 6;
  const int lane = tid & 63;
  const int bm = blockIdx.x * 32;
  const int arow = tid >> 4;
  const int akk = tid & 15;
  const int bkr = tid >> 5;
  const int bc = (tid & 31) * 8;
  float acc[4][4] = {};
  for (int k0 = 0; k0 < KIN; k0 += 16) {
    float av = h[(size_t)(bm + arow) * KIN + k0 + akk];
    const float4* wp = (const float4*)(W + (size_t)(k0 + bkr) * KOUT + bc);
    float4 w0 = wp[0], w1 = wp[1];
    __syncthreads();
    sA[akk][arow] = av;
    *(float4*)&sB[bkr][bc] = w0;
    *(float4*)&sB[bkr][bc + 4] = w1;
    __syncthreads();
#pragma unroll
    for (int k = 0; k < 16; ++k) {
      float4 a4 = *(const float4*)&sA[k][wave * 4];
      float4 b4 = *(const float4*)&sB[k][lane * 4];
      float aa[4] = {a4.x, a4.y, a4.z, a4.w};
      float bb[4] = {b4.x, b4.y, b4.z, b4.w};
#pragma unroll
      for (int i = 0; i < 4; ++i)
#pragma unroll
        for (int jj = 0; jj < 4; ++jj)
          acc[i][jj] = fmaf(aa[i], bb[jj], acc[i][jj]);
    }
  }
  float4 a1v = *(const float4*)(a1 + lane * 4);
  float4 a2v = *(const float4*)(a2 + lane * 4);
  float sp[4], dp[4];
#pragma unroll
  for (int i = 0; i < 4; ++i) {
    sp[i] = acc[i][0] * a1v.x + acc[i][1] * a1v.y + acc[i][2] * a1v.z + acc[i][3] * a1v.w;
    dp[i] = acc[i][0] * a2v.x + acc[i][1] * a2v.y + acc[i][2] * a2v.z + acc[i][3] * a2v.w;
  }
#pragma unroll
  for (int off = 32; off >= 1; off >>= 1) {
#pragma unroll
    for (int i = 0; i < 4; ++i) {
      sp[i] += __shfl_xor(sp[i], off);
      dp[i] += __shfl_xor(dp[i], off);
    }
  }
  if (lane == 0) {
#pragma unroll
    for (int i = 0; i < 4; ++i) {
      src[bm + wave * 4 + i] = sp[i];
      dstv[bm + wave * 4 + i] = dp[i];
    }
  }
#pragma unroll
  for (int i = 0; i < 4; ++i) {
    ushort4_t pk;
#pragma unroll
    for (int jj = 0; jj < 4; ++jj) pk[jj] = f2bf(acc[i][jj]);
    *(ushort4_t*)(WhB + (size_t)(bm + wave * 4 + i) * KOUT + lane * 4) = pk;
  }
}

// ---------------- k_tr: WhT[c][r] = WhB[r][c] ----------------
__global__ __launch_bounds__(256) void k_tr(const unsigned short* __restrict__ WhB,
                                            unsigned short* __restrict__ WhT) {
  __shared__ unsigned int sX[64][65];
  const int t = threadIdx.x;
  const int r0 = (blockIdx.x & 127) * 64;
  const int c0 = (blockIdx.x >> 7) * 64;
  const int rr = t >> 2;
  const int cq = (t & 3) * 16;
  const ushort8_t* p = (const ushort8_t*)(WhB + (size_t)(r0 + rr) * KOUT + c0 + cq);
  ushort8_t v0 = p[0], v1 = p[1];
#pragma unroll
  for (int i = 0; i < 8; ++i) {
    sX[rr][cq + i] = v0[i];
    sX[rr][cq + 8 + i] = v1[i];
  }
  __syncthreads();
  const int cc = t >> 2;
  const int r8 = (t & 3) * 16;
  ushort8_t o0, o1;
#pragma unroll
  for (int i = 0; i < 8; ++i) {
    o0[i] = (unsigned short)sX[r8 + i][cc];
    o1[i] = (unsigned short)sX[r8 + 8 + i][cc];
  }
  ushort8_t* q = (ushort8_t*)(WhT + (size_t)(c0 + cc) * NN + r0 + r8);
  q[0] = o0;
  q[1] = o1;
}

// ---------------- k_dmax ----------------
__global__ __launch_bounds__(256) void k_dmax(const float* __restrict__ dstv,
                                              float* __restrict__ Dp) {
  __shared__ float red[256];
  const int t = threadIdx.x;
  float m = -3e38f;
  for (int i = t; i < NN; i += 256) m = fmaxf(m, dstv[i]);
  red[t] = m;
  __syncthreads();
  for (int s = 128; s >= 1; s >>= 1) {
    if (t < s) red[t] = fmaxf(red[t], red[t + s]);
    __syncthreads();
  }
  if (t == 0) *Dp = red[0];
}

// ---- k_attn: wave-specialized producer/consumer, 4-deep A ring -----------
struct Bset { ushort8_t b[2][2]; };  // [col-half][kk]

#define MF(a, b, c) __builtin_amdgcn_mfma_f32_16x16x32_bf16(a, b, c, 0, 0, 0)

// barrier that does NOT drain vmcnt (keeps prefetches in flight)
#define BAR()                                              \
  {                                                        \
    asm volatile("s_waitcnt lgkmcnt(0)" ::: "memory");     \
    __builtin_amdgcn_s_barrier();                          \
    asm volatile("" ::: "memory");                         \
  }

// virtual phase t -> physical k-tile (per-block rotation decontends L2)
#define TI(t) (((t) + ph0) & (NT - 1))

#define LOADB(BS, kt)                                                  \
  {                                                                    \
    const size_t kb = (size_t)(kt) * BK + fq * 8;                      \
    BS.b[0][0] = *(const ushort8_t*)(bpw0 + kb);                       \
    BS.b[0][1] = *(const ushort8_t*)(bpw0 + kb + 32);                  \
    BS.b[1][0] = *(const ushort8_t*)(bpw1 + kb);                       \
    BS.b[1][1] = *(const ushort8_t*)(bpw1 + kb + 32);                  \
  }

// producer: thread owns (row pr, k-quad pk4); dstv from LDS
#define WGEN4(AJ, kt, buf)                                             \
  {                                                                    \
    float4 dv = *(const float4*)&sD[(kt) * BK + pk4];                  \
    float w0 = (AJ.x > 0) ? __expf(lrelu(s_r + dv.x) - c_r) : 0.f;     \
    float w1 = (AJ.y > 0) ? __expf(lrelu(s_r + dv.y) - c_r) : 0.f;     \
    float w2 = (AJ.z > 0) ? __expf(lrelu(s_r + dv.z) - c_r) : 0.f;     \
    float w3 = (AJ.w > 0) ? __expf(lrelu(s_r + dv.w) - c_r) : 0.f;     \
    unsigned short u0 = f2bf(w0), u1 = f2bf(w1);                       \
    unsigned short u2 = f2bf(w2), u3 = f2bf(w3);                       \
    lsum += bf2f(u0) + bf2f(u1) + bf2f(u2) + bf2f(u3);                 \
    uint2 pk;                                                          \
    pk.x = (unsigned)u0 | ((unsigned)u1 << 16);                        \
    pk.y = (unsigned)u2 | ((unsigned)u3 << 16);                        \
    *(uint2*)(sAb + (buf) * 4096 + wbyte) = pk;                        \
  }

#define LDA(cur, mr, kk)                                                        \
  __builtin_bit_cast(bf16x8,                                                    \
    *(const ushort8_t*)(sAb + (cur) * 4096 +                                    \
      ((((mr) * 16 + fr) * 128 + (kk) * 64 + fq * 16) ^ ((fr & 7) << 4))))

#define MSTEP(cur, BS)                                                 \
  {                                                                    \
    bf16x8 a00 = LDA(cur, 0, 0), a01 = LDA(cur, 0, 1);                 \
    bf16x8 a10 = LDA(cur, 1, 0), a11 = LDA(cur, 1, 1);                 \
    acc00 = MF(a00, BS.b[0][0], acc00);                                \
    acc00 = MF(a01, BS.b[0][1], acc00);                                \
    acc01 = MF(a00, BS.b[1][0], acc01);                                \
    acc01 = MF(a01, BS.b[1][1], acc01);                                \
    acc10 = MF(a10, BS.b[0][0], acc10);                                \
    acc10 = MF(a11, BS.b[0][1], acc10);                                \
    acc11 = MF(a10, BS.b[1][0], acc11);                                \
    acc11 = MF(a11, BS.b[1][1], acc11);                                \
  }

// consumer sub-phase: MFMA tile p+s from buf s, refill B <- tile p+s+2
#define CSTEP(s, BS)                                                   \
  {                                                                    \
    MSTEP((s), BS);                                                    \
    LOADB(BS, TI(p + (s) + 2));                                        \
    BAR();                                                             \
  }

// producer sub-phase: gen tile p+s+2 -> buf (s+2)&3; refill adj <- tile p+s+6
#define PSTEP(s, AJ)                                                   \
  {                                                                    \
    if (p + (s) + 2 < NT) { WGEN4(AJ, TI(p + (s) + 2), ((s) + 2) & 3); } \
    AJ = __builtin_nontemporal_load(                                   \
        (const int4v*)(adjp + (size_t)TI(p + (s) + 6) * BK));          \
    BAR();                                                             \
  }

__global__ __launch_bounds__(1024) void k_attn(const int* __restrict__ adj,
                                               const unsigned short* __restrict__ WhT,
                                               const float* __restrict__ src,
                                               const float* __restrict__ dstv,
                                               const float* __restrict__ Dp,
                                               float* __restrict__ out) {
  __shared__ unsigned short sA[4][32][BK];  // 16 KB ring, XOR-swizzled rows
  __shared__ float sD[NN];                  // 32 KB: dstv staged once
  __shared__ float sL[32];
  char* sAb = (char*)&sA[0][0][0];
  const int tid = threadIdx.x;
  const int lane = tid & 63;
  const int wave = tid >> 6;      // 0..15: waves 0-7 consumers, 8-15 producers
  const int r0 = blockIdx.x * 32;
  const int ph0 = blockIdx.x & (NT - 1);
  const float D = *Dp;

  // stage dstv -> LDS (coalesced, once, all threads)
  {
    float4 v0 = *(const float4*)(dstv + tid * 8);
    float4 v1 = *(const float4*)(dstv + tid * 8 + 4);
    *(float4*)&sD[tid * 8] = v0;
    *(float4*)&sD[tid * 8 + 4] = v1;
  }
  __syncthreads();

  // ---------- producer state (waves 8..15) ----------
  const int ptid = tid - 512;               // 0..511 for producers
  const int pr = (ptid & 511) >> 4;         // 0..31
  const int pk4 = (ptid & 15) * 4;          // k-quad
  const float s_r = src[r0 + pr];
  const float c_r = lrelu(s_r + D);
  const int* adjp = adj + (size_t)(r0 + pr) * NN + pk4;
  const int wbyte = ((pr * (BK * 2) + pk4 * 2) ^ ((pr & 7) << 4));
  float lsum = 0.f;

  // ---------- consumer state (waves 0..7) ----------
  const int fr = lane & 15;
  const int fq = lane >> 4;
  const unsigned short* bpw0 = WhT + (size_t)(wave * 32 + fr) * NN;
  const unsigned short* bpw1 = WhT + (size_t)(wave * 32 + 16 + fr) * NN;
  f32x4 acc00 = {0.f, 0.f, 0.f, 0.f};
  f32x4 acc01 = acc00, acc10 = acc00, acc11 = acc00;
  Bset B0, B1;
  int4v adjS0, adjS1, adjS2, adjS3;

  // ---------- prologue ----------
  if (wave >= 8) {
    // gen tiles 0,1 -> buf0,1 (direct adj loads)
    int4v a0 = *(const int4v*)(adjp + (size_t)TI(0) * BK);
    int4v a1 = *(const int4v*)(adjp + (size_t)TI(1) * BK);
    WGEN4(a0, TI(0), 0);
    WGEN4(a1, TI(1), 1);
    // preload adj for tiles 2,3,4,5 -> slots 2,3,0,1 (slot = tile & 3)
    adjS2 = __builtin_nontemporal_load((const int4v*)(adjp + (size_t)TI(2) * BK));
    adjS3 = __builtin_nontemporal_load((const int4v*)(adjp + (size_t)TI(3) * BK));
    adjS0 = __builtin_nontemporal_load((const int4v*)(adjp + (size_t)TI(4) * BK));
    adjS1 = __builtin_nontemporal_load((const int4v*)(adjp + (size_t)TI(5) * BK));
  } else {
    LOADB(B0, TI(0));
    LOADB(B1, TI(1));
  }
  BAR();

  // ---------- main loop: 128 phases, unrolled by 4 for static slots ----------
  if (wave < 8) {
#pragma unroll 1
    for (int p = 0; p < NT; p += 4) {
      CSTEP(0, B0);
      CSTEP(1, B1);
      CSTEP(2, B0);
      CSTEP(3, B1);
    }
  } else {
#pragma unroll 1
    for (int p = 0; p < NT; p += 4) {
      PSTEP(0, adjS2);
      PSTEP(1, adjS3);
      PSTEP(2, adjS0);
      PSTEP(3, adjS1);
    }
    // row-sum reduce across the 16 threads sharing a row
#pragma unroll
    for (int off = 1; off <= 8; off <<= 1) lsum += __shfl_xor(lsum, off, 16);
    if ((ptid & 15) == 0) sL[pr] = lsum;
  }
  __syncthreads();

  // ---------- epilogue: consumers normalize, ELU, store ----------
  if (wave < 8) {
    const f32x4 accs[2][2] = {{acc00, acc01}, {acc10, acc11}};
#pragma unroll
    for (int mr = 0; mr < 2; ++mr) {
#pragma unroll
      for (int r = 0; r < 4; ++r) {
        const int row = mr * 16 + fq * 4 + r;
        const float l = sL[row];
#pragma unroll
        for (int nc = 0; nc < 2; ++nc) {
          const int col = wave * 32 + nc * 16 + fr;
          float v = accs[mr][nc][r] / l;
          v = v > 0.f ? v : __expf(v) - 1.f;
          out[(size_t)(r0 + row) * KOUT + col] = v;
        }
      }
    }
  }
}

extern "C" void kernel_launch(void* const* d_in, const int* in_sizes, int n_in,
                              void* d_out, int out_size, void* d_ws, size_t ws_size,
                              hipStream_t stream) {
  const float* h = (const float*)d_in[0];
  const int* adj = (const int*)d_in[1];
  const float* W = (const float*)d_in[2];
  const float* a1 = (const float*)d_in[3];
  const float* a2 = (const float*)d_in[4];
  float* out = (float*)d_out;

  unsigned short* WhB = (unsigned short*)d_ws;
  unsigned short* WhT = WhB + (size_t)NN * KOUT;
  float* src = (float*)(WhT + (size_t)NN * KOUT);
  float* dstv = src + NN;
  float* Dp = dstv + NN;

  hipLaunchKernelGGL(k_wh, dim3(NN / 32), dim3(512), 0, stream, h, W, a1, a2, WhB, src, dstv);
  hipLaunchKernelGGL(k_tr, dim3(512), dim3(256), 0, stream, WhB, WhT);
  hipLaunchKernelGGL(k_dmax, dim3(1), dim3(256), 0, stream, dstv, Dp);
  hipLaunchKernelGGL(k_attn, dim3(NN / 32), dim3(1024), 0, stream, adj, WhT, src, dstv, Dp, out);
}